// Round 3
// baseline (9712.540 us; speedup 1.0000x reference)
//
#include <hip/hip_runtime.h>

#define NN 100000
#define NE 1600000
#define ET (NE + NN)   // edges + self-loops = 1,700,000

// ---- ordered-uint encoding for float atomicMax (bijective, monotone) ----
__device__ __forceinline__ unsigned enc_f32(float v) {
    unsigned b = __float_as_uint(v);
    return b ^ ((b & 0x80000000u) ? 0xFFFFFFFFu : 0x80000000u);
}
__device__ __forceinline__ float dec_f32(unsigned u) {
    unsigned b = (u & 0x80000000u) ? (u ^ 0x80000000u) : ~u;
    return __uint_as_float(b);
}

// ---- h0 = relu(x @ W_in + b_in), x[N,256], W[256,32] ----
// 8 threads/row, 4 cols each. Grid = NN*8/256 = 3125 blocks.
__global__ void lin_relu(const float* __restrict__ x, const float* __restrict__ W,
                         const float* __restrict__ b, float* __restrict__ h) {
    int tid = blockIdx.x * 256 + threadIdx.x;
    int row = tid >> 3;
    int c0  = (tid & 7) * 4;
    if (row >= NN) return;
    const float* xr = x + (long long)row * 256;
    float4 acc = {0.f, 0.f, 0.f, 0.f};
    for (int k = 0; k < 256; ++k) {
        float xv = xr[k];
        float4 wv = *(const float4*)(W + k * 32 + c0);
        acc.x += xv * wv.x; acc.y += xv * wv.y;
        acc.z += xv * wv.z; acc.w += xv * wv.w;
    }
    float4 bv = *(const float4*)(b + c0);
    acc.x = fmaxf(acc.x + bv.x, 0.f);
    acc.y = fmaxf(acc.y + bv.y, 0.f);
    acc.z = fmaxf(acc.z + bv.z, 0.f);
    acc.w = fmaxf(acc.w + bv.w, 0.f);
    *(float4*)(h + (long long)row * 32 + c0) = acc;
}

// ---- hp = hin @ W  [K x 128]; also e_src/e_dst logits per (node, head) ----
// 32 threads/row (4 cols each), 8 rows/block. Grid = NN*32/256 = 12500.
template<int K>
__global__ void gemm_att(const float* __restrict__ hin, const float* __restrict__ W,
                         const float* __restrict__ asrc, const float* __restrict__ adst,
                         float* __restrict__ hp, float* __restrict__ es,
                         float* __restrict__ ed) {
    int tid = blockIdx.x * 256 + threadIdx.x;
    int row = tid >> 5;
    int t   = tid & 31;
    int c0  = t * 4;
    int head = t >> 3;
    if (row >= NN) return;
    const float* hr = hin + (long long)row * K;
    float4 acc = {0.f, 0.f, 0.f, 0.f};
    for (int k = 0; k < K; ++k) {
        float hv = hr[k];
        float4 wv = *(const float4*)(W + k * 128 + c0);
        acc.x += hv * wv.x; acc.y += hv * wv.y;
        acc.z += hv * wv.z; acc.w += hv * wv.w;
    }
    *(float4*)(hp + (long long)row * 128 + c0) = acc;

    int d0 = (t & 7) * 4;
    float4 as4 = *(const float4*)(asrc + head * 32 + d0);
    float4 ad4 = *(const float4*)(adst + head * 32 + d0);
    float ps = acc.x * as4.x + acc.y * as4.y + acc.z * as4.z + acc.w * as4.w;
    float pd = acc.x * ad4.x + acc.y * ad4.y + acc.z * ad4.z + acc.w * ad4.w;
    for (int off = 1; off < 8; off <<= 1) {
        ps += __shfl_xor(ps, off, 8);
        pd += __shfl_xor(pd, off, 8);
    }
    if ((t & 7) == 0) {
        es[row * 4 + head] = ps;
        ed[row * 4 + head] = pd;
    }
}

// ---- segment max of leaky_relu(es[src]+ed[dst]) into m[dst] (encoded uint) ----
__global__ void edge_max(const int* __restrict__ ei, const float* __restrict__ es,
                         const float* __restrict__ ed, unsigned* __restrict__ m) {
    long long idx = (long long)blockIdx.x * 256 + threadIdx.x;
    if (idx >= (long long)ET * 4) return;
    int e = (int)(idx >> 2), head = (int)(idx & 3);
    int src, dst;
    if (e < NE) { src = ei[e]; dst = ei[NE + e]; }
    else        { src = dst = e - NE; }
    float xv = es[src * 4 + head] + ed[dst * 4 + head];
    float ev = xv > 0.f ? xv : 0.2f * xv;
    atomicMax(m + dst * 4 + head, enc_f32(ev));
}

// ---- acc[dst] += exp(e - m[dst]) * hp[src];  s[dst] += exp(e - m[dst]) ----
// 32 lanes/edge (float4 each), 8 edges/block. Grid = ET/8 = 212500 (exact).
__global__ void edge_accum(const int* __restrict__ ei, const float* __restrict__ es,
                           const float* __restrict__ ed, const unsigned* __restrict__ m,
                           const float* __restrict__ hp,
                           float* __restrict__ s, float* __restrict__ acc) {
    int e = blockIdx.x * 8 + (threadIdx.x >> 5);
    int t = threadIdx.x & 31;
    int head = t >> 3;
    int src, dst;
    if (e < NE) { src = ei[e]; dst = ei[NE + e]; }
    else        { src = dst = e - NE; }
    float xv = es[src * 4 + head] + ed[dst * 4 + head];
    float ev = xv > 0.f ? xv : 0.2f * xv;
    float mv = dec_f32(m[dst * 4 + head]);
    float w = __expf(ev - mv);
    if ((t & 7) == 0) atomicAdd(s + dst * 4 + head, w);
    float4 hv = *(const float4*)(hp + (long long)src * 128 + t * 4);
    float* ao = acc + (long long)dst * 128 + t * 4;
    atomicAdd(ao + 0, w * hv.x);
    atomicAdd(ao + 1, w * hv.y);
    atomicAdd(ao + 2, w * hv.z);
    atomicAdd(ao + 3, w * hv.w);
}

// ---- out = elu(acc/(s+1e-16) + b), in-place capable ----
__global__ void finalize(const float* __restrict__ acc, const float* __restrict__ s,
                         const float* __restrict__ b, float* __restrict__ out) {
    int idx = blockIdx.x * 256 + threadIdx.x;  // NN*32 threads
    int n = idx >> 5, t = idx & 31;
    if (n >= NN) return;
    int head = t >> 3, c0 = t * 4;
    float sv = s[n * 4 + head] + 1e-16f;
    float4 a = *(const float4*)(acc + (long long)n * 128 + c0);
    float4 bv = *(const float4*)(b + c0);
    float4 v;
    v.x = a.x / sv + bv.x;
    v.y = a.y / sv + bv.y;
    v.z = a.z / sv + bv.z;
    v.w = a.w / sv + bv.w;
    v.x = v.x > 0.f ? v.x : expm1f(v.x);
    v.y = v.y > 0.f ? v.y : expm1f(v.y);
    v.z = v.z > 0.f ? v.z : expm1f(v.z);
    v.w = v.w > 0.f ? v.w : expm1f(v.w);
    *(float4*)(out + (long long)n * 128 + c0) = v;
}

extern "C" void kernel_launch(void* const* d_in, const int* in_sizes, int n_in,
                              void* d_out, int out_size, void* d_ws, size_t ws_size,
                              hipStream_t stream) {
    const float* x    = (const float*)d_in[0];
    const int*   ei   = (const int*)d_in[1];
    const float* W_in = (const float*)d_in[2];
    const float* b_in = (const float*)d_in[3];
    const float* W[3]  = {(const float*)d_in[4], (const float*)d_in[8],  (const float*)d_in[12]};
    const float* As[3] = {(const float*)d_in[5], (const float*)d_in[9],  (const float*)d_in[13]};
    const float* Ad[3] = {(const float*)d_in[6], (const float*)d_in[10], (const float*)d_in[14]};
    const float* Bs[3] = {(const float*)d_in[7], (const float*)d_in[11], (const float*)d_in[15]};

    // Workspace layout (~70.4 MB): accb aliases d_out (NN*128 f32 = out_size).
    float* h0   = (float*)d_ws;                      // NN*32
    float* hp   = h0   + (size_t)NN * 32;            // NN*128
    float* es   = hp   + (size_t)NN * 128;           // NN*4
    float* ed   = es   + (size_t)NN * 4;             // NN*4
    unsigned* m = (unsigned*)(ed + (size_t)NN * 4);  // NN*4
    float* s    = (float*)(m + (size_t)NN * 4);      // NN*4
    float* accb = (float*)d_out;                     // NN*128 (final layer ends here)

    lin_relu<<<3125, 256, 0, stream>>>(x, W_in, b_in, h0);

    const float* in = h0;
    for (int l = 0; l < 3; ++l) {
        if (l == 0)
            gemm_att<32><<<12500, 256, 0, stream>>>(in, W[0], As[0], Ad[0], hp, es, ed);
        else
            gemm_att<128><<<12500, 256, 0, stream>>>(in, W[l], As[l], Ad[l], hp, es, ed);
        hipMemsetAsync(m, 0, (size_t)NN * 4 * sizeof(unsigned), stream);
        hipMemsetAsync(s, 0, (size_t)NN * 4 * sizeof(float), stream);
        hipMemsetAsync(accb, 0, (size_t)NN * 128 * sizeof(float), stream);
        edge_max<<<(int)(((long long)ET * 4 + 255) / 256), 256, 0, stream>>>(ei, es, ed, m);
        edge_accum<<<ET / 8, 256, 0, stream>>>(ei, es, ed, m, hp, s, accb);
        finalize<<<12500, 256, 0, stream>>>(accb, s, Bs[l], accb);
        in = accb;
    }
}

// Round 4
// 1463.113 us; speedup vs baseline: 6.6383x; 6.6383x over previous
//
#include <hip/hip_runtime.h>

#define NN 100000
#define NE 1600000
#define ET (NE + NN)   // edges + self-loops = 1,700,000

// ============================ dense layers ============================

// ---- h0 = relu(x @ W_in + b_in), x[N,256], W[256,32] ----
__global__ void lin_relu(const float* __restrict__ x, const float* __restrict__ W,
                         const float* __restrict__ b, float* __restrict__ h) {
    int tid = blockIdx.x * 256 + threadIdx.x;
    int row = tid >> 3;
    int c0  = (tid & 7) * 4;
    if (row >= NN) return;
    const float* xr = x + (long long)row * 256;
    float4 acc = {0.f, 0.f, 0.f, 0.f};
    for (int k = 0; k < 256; ++k) {
        float xv = xr[k];
        float4 wv = *(const float4*)(W + k * 32 + c0);
        acc.x += xv * wv.x; acc.y += xv * wv.y;
        acc.z += xv * wv.z; acc.w += xv * wv.w;
    }
    float4 bv = *(const float4*)(b + c0);
    acc.x = fmaxf(acc.x + bv.x, 0.f);
    acc.y = fmaxf(acc.y + bv.y, 0.f);
    acc.z = fmaxf(acc.z + bv.z, 0.f);
    acc.w = fmaxf(acc.w + bv.w, 0.f);
    *(float4*)(h + (long long)row * 32 + c0) = acc;
}

// ---- hp = hin @ W [K x 128]; also per-(node,head) logits es/ed ----
template<int K>
__global__ void gemm_att(const float* __restrict__ hin, const float* __restrict__ W,
                         const float* __restrict__ asrc, const float* __restrict__ adst,
                         float* __restrict__ hp, float* __restrict__ es,
                         float* __restrict__ ed) {
    int tid = blockIdx.x * 256 + threadIdx.x;
    int row = tid >> 5;
    int t   = tid & 31;
    int c0  = t * 4;
    int head = t >> 3;
    if (row >= NN) return;
    const float* hr = hin + (long long)row * K;
    float4 acc = {0.f, 0.f, 0.f, 0.f};
    for (int k = 0; k < K; ++k) {
        float hv = hr[k];
        float4 wv = *(const float4*)(W + k * 128 + c0);
        acc.x += hv * wv.x; acc.y += hv * wv.y;
        acc.z += hv * wv.z; acc.w += hv * wv.w;
    }
    *(float4*)(hp + (long long)row * 128 + c0) = acc;

    int d0 = (t & 7) * 4;
    float4 as4 = *(const float4*)(asrc + head * 32 + d0);
    float4 ad4 = *(const float4*)(adst + head * 32 + d0);
    float ps = acc.x * as4.x + acc.y * as4.y + acc.z * as4.z + acc.w * as4.w;
    float pd = acc.x * ad4.x + acc.y * ad4.y + acc.z * ad4.z + acc.w * ad4.w;
    for (int off = 1; off < 8; off <<= 1) {
        ps += __shfl_xor(ps, off, 8);
        pd += __shfl_xor(pd, off, 8);
    }
    if ((t & 7) == 0) {
        es[row * 4 + head] = ps;
        ed[row * 4 + head] = pd;
    }
}

// ============================ CSR build (once) ============================

__global__ void count_deg(const int* __restrict__ ei, int* __restrict__ deg) {
    int e = blockIdx.x * 256 + threadIdx.x;
    if (e >= ET) return;
    int dst = (e < NE) ? ei[NE + e] : e - NE;
    atomicAdd(deg + dst, 1);
}

// single-workgroup exclusive scan over deg[NN] -> row_ptr[NN+1]
#define SCAN_T 1024
#define CHUNK 98            // 1024*98 = 100352 >= NN
__global__ __launch_bounds__(SCAN_T) void scan_deg(const int* __restrict__ deg,
                                                   int* __restrict__ row_ptr) {
    __shared__ int ps[SCAN_T];
    int t = threadIdx.x;
    int base = t * CHUNK;
    int s = 0;
    for (int i = 0; i < CHUNK; ++i) {
        int idx = base + i;
        if (idx < NN) s += deg[idx];
    }
    ps[t] = s;
    __syncthreads();
    for (int off = 1; off < SCAN_T; off <<= 1) {
        int v = (t >= off) ? ps[t - off] : 0;
        __syncthreads();
        ps[t] += v;
        __syncthreads();
    }
    int run = (t == 0) ? 0 : ps[t - 1];
    for (int i = 0; i < CHUNK; ++i) {
        int idx = base + i;
        if (idx < NN) { row_ptr[idx] = run; run += deg[idx]; }
    }
    if (t == SCAN_T - 1) row_ptr[NN] = run;
}

__global__ void fill_csr(const int* __restrict__ ei, int* __restrict__ cursor,
                         int* __restrict__ col) {
    int e = blockIdx.x * 256 + threadIdx.x;
    if (e >= ET) return;
    int src, dst;
    if (e < NE) { src = ei[e]; dst = ei[NE + e]; }
    else        { src = dst = e - NE; }
    int pos = atomicAdd(cursor + dst, 1);
    col[pos] = src;
}

// ==================== fused softmax-aggregate (no atomics) ====================
// 32 lanes per dst node (2 nodes/wave, 8 nodes/block). Grid = NN*32/256 = 12500.
__global__ void gat_aggregate(const int* __restrict__ row_ptr, const int* __restrict__ col,
                              const float* __restrict__ es, const float* __restrict__ ed,
                              const float* __restrict__ hp, const float* __restrict__ b,
                              float* __restrict__ out) {
    int tid = blockIdx.x * 256 + threadIdx.x;
    int n = tid >> 5;
    int t = tid & 31;
    if (n >= NN) return;
    int head = t >> 3;
    int beg = row_ptr[n], end = row_ptr[n + 1];

    float4 ed4 = *(const float4*)(ed + n * 4);
    // phase 1: per-head max over in-edges (lane-strided)
    float4 m4 = {-1e30f, -1e30f, -1e30f, -1e30f};
    for (int i = beg + t; i < end; i += 32) {
        int s = col[i];
        float4 l = *(const float4*)(es + s * 4);
        l.x += ed4.x; l.y += ed4.y; l.z += ed4.z; l.w += ed4.w;
        l.x = l.x > 0.f ? l.x : 0.2f * l.x;
        l.y = l.y > 0.f ? l.y : 0.2f * l.y;
        l.z = l.z > 0.f ? l.z : 0.2f * l.z;
        l.w = l.w > 0.f ? l.w : 0.2f * l.w;
        m4.x = fmaxf(m4.x, l.x); m4.y = fmaxf(m4.y, l.y);
        m4.z = fmaxf(m4.z, l.z); m4.w = fmaxf(m4.w, l.w);
    }
    for (int off = 1; off < 32; off <<= 1) {
        m4.x = fmaxf(m4.x, __shfl_xor(m4.x, off, 32));
        m4.y = fmaxf(m4.y, __shfl_xor(m4.y, off, 32));
        m4.z = fmaxf(m4.z, __shfl_xor(m4.z, off, 32));
        m4.w = fmaxf(m4.w, __shfl_xor(m4.w, off, 32));
    }
    float m = (head == 0) ? m4.x : (head == 1) ? m4.y : (head == 2) ? m4.z : m4.w;
    float edv = (head == 0) ? ed4.x : (head == 1) ? ed4.y : (head == 2) ? ed4.z : ed4.w;

    // phase 2: serial walk; all 32 lanes cooperate per edge (512B coalesced gather)
    float4 acc = {0.f, 0.f, 0.f, 0.f};
    float ws = 0.f;
    for (int i = beg; i < end; ++i) {
        int s = col[i];
        float lv = es[s * 4 + head] + edv;
        lv = lv > 0.f ? lv : 0.2f * lv;
        float w = __expf(lv - m);
        ws += w;
        float4 hv = *(const float4*)(hp + (long long)s * 128 + t * 4);
        acc.x += w * hv.x; acc.y += w * hv.y;
        acc.z += w * hv.z; acc.w += w * hv.w;
    }
    float sv = ws + 1e-16f;
    float4 bv = *(const float4*)(b + t * 4);
    float4 v;
    v.x = acc.x / sv + bv.x;
    v.y = acc.y / sv + bv.y;
    v.z = acc.z / sv + bv.z;
    v.w = acc.w / sv + bv.w;
    v.x = v.x > 0.f ? v.x : expm1f(v.x);
    v.y = v.y > 0.f ? v.y : expm1f(v.y);
    v.z = v.z > 0.f ? v.z : expm1f(v.z);
    v.w = v.w > 0.f ? v.w : expm1f(v.w);
    *(float4*)(out + (long long)n * 128 + t * 4) = v;
}

// ============================ host ============================

extern "C" void kernel_launch(void* const* d_in, const int* in_sizes, int n_in,
                              void* d_out, int out_size, void* d_ws, size_t ws_size,
                              hipStream_t stream) {
    const float* x    = (const float*)d_in[0];
    const int*   ei   = (const int*)d_in[1];
    const float* W_in = (const float*)d_in[2];
    const float* b_in = (const float*)d_in[3];
    const float* W[3]  = {(const float*)d_in[4], (const float*)d_in[8],  (const float*)d_in[12]};
    const float* As[3] = {(const float*)d_in[5], (const float*)d_in[9],  (const float*)d_in[13]};
    const float* Ad[3] = {(const float*)d_in[6], (const float*)d_in[10], (const float*)d_in[14]};
    const float* Bs[3] = {(const float*)d_in[7], (const float*)d_in[11], (const float*)d_in[15]};

    // workspace layout (~75 MB); accb aliases d_out
    float* h0     = (float*)d_ws;                       // NN*32
    float* hp     = h0 + (size_t)NN * 32;               // NN*128
    float* es     = hp + (size_t)NN * 128;              // NN*4
    float* ed     = es + (size_t)NN * 4;                // NN*4
    int*   row_ptr= (int*)(ed + (size_t)NN * 4);        // NN+1
    int*   deg    = row_ptr + (NN + 1);                 // NN
    int*   cursor = deg + NN;                           // NN
    int*   colb   = cursor + NN;                        // ET
    float* accb   = (float*)d_out;                      // NN*128

    // ---- CSR build (graph is static across layers) ----
    hipMemsetAsync(deg, 0, (size_t)NN * sizeof(int), stream);
    count_deg<<<(ET + 255) / 256, 256, 0, stream>>>(ei, deg);
    scan_deg<<<1, SCAN_T, 0, stream>>>(deg, row_ptr);
    hipMemcpyAsync(cursor, row_ptr, (size_t)NN * sizeof(int),
                   hipMemcpyDeviceToDevice, stream);
    fill_csr<<<(ET + 255) / 256, 256, 0, stream>>>(ei, cursor, colb);

    lin_relu<<<3125, 256, 0, stream>>>(x, W_in, b_in, h0);

    const float* in = h0;
    for (int l = 0; l < 3; ++l) {
        if (l == 0)
            gemm_att<32><<<12500, 256, 0, stream>>>(in, W[0], As[0], Ad[0], hp, es, ed);
        else
            gemm_att<128><<<12500, 256, 0, stream>>>(in, W[l], As[l], Ad[l], hp, es, ed);
        gat_aggregate<<<12500, 256, 0, stream>>>(row_ptr, colb, es, ed, hp, Bs[l], accb);
        in = accb;
    }
}

// Round 5
// 1035.618 us; speedup vs baseline: 9.3785x; 1.4128x over previous
//
#include <hip/hip_runtime.h>

#define NN 100000
#define NE 1600000
#define ET (NE + NN)   // edges + self-loops = 1,700,000

// ============================ dense layers ============================

// ---- h0 = relu(x @ W_in + b_in): x[N,256], W[256,32]. ----
// W_in staged in LDS (32 KB). 1 row/thread, 4 cols; x read as float4.
__global__ __launch_bounds__(256) void lin_relu2(const float* __restrict__ x,
                                                 const float* __restrict__ W,
                                                 const float* __restrict__ b,
                                                 float* __restrict__ h) {
    __shared__ float Wl[256 * 32];
    int t = threadIdx.x;
    for (int j = 0; j < 8; ++j) {
        int f = t + 256 * j;                 // f < 2048 float4s
        *(float4*)&Wl[f * 4] = *(const float4*)(W + f * 4);
    }
    __syncthreads();

    int row = (blockIdx.x * 256 + t) >> 3;   // 800000/8 = 100000 exactly
    int c0  = (t & 7) * 4;
    const float* xr = x + (long long)row * 256;
    float4 acc = {0.f, 0.f, 0.f, 0.f};
    for (int k4 = 0; k4 < 64; ++k4) {
        float4 xv = *(const float4*)(xr + k4 * 4);
        float4 w0 = *(const float4*)&Wl[(k4 * 4 + 0) * 32 + c0];
        float4 w1 = *(const float4*)&Wl[(k4 * 4 + 1) * 32 + c0];
        float4 w2 = *(const float4*)&Wl[(k4 * 4 + 2) * 32 + c0];
        float4 w3 = *(const float4*)&Wl[(k4 * 4 + 3) * 32 + c0];
        acc.x += xv.x * w0.x + xv.y * w1.x + xv.z * w2.x + xv.w * w3.x;
        acc.y += xv.x * w0.y + xv.y * w1.y + xv.z * w2.y + xv.w * w3.y;
        acc.z += xv.x * w0.z + xv.y * w1.z + xv.z * w2.z + xv.w * w3.z;
        acc.w += xv.x * w0.w + xv.y * w1.w + xv.z * w2.w + xv.w * w3.w;
    }
    float4 bv = *(const float4*)(b + c0);
    acc.x = fmaxf(acc.x + bv.x, 0.f);
    acc.y = fmaxf(acc.y + bv.y, 0.f);
    acc.z = fmaxf(acc.z + bv.z, 0.f);
    acc.w = fmaxf(acc.w + bv.w, 0.f);
    *(float4*)(h + (long long)row * 32 + c0) = acc;
}

// ---- hp = hin @ W [K x 128] + es/ed logits. Register-blocked: ----
// 64 rows/block; thread = 8 rows x 4 cols (32 f32 acc). hin tile in LDS.
template<int K>
__global__ __launch_bounds__(256) void gemm_att2(const float* __restrict__ hin,
                                                 const float* __restrict__ W,
                                                 const float* __restrict__ asrc,
                                                 const float* __restrict__ adst,
                                                 float* __restrict__ hp,
                                                 float* __restrict__ es,
                                                 float* __restrict__ ed) {
    __shared__ float hl[64][K + 4];
    int t = threadIdx.x;
    int base = blockIdx.x * 64;

    // stage 64 rows of hin (row-major, b128 in/out)
    if (K == 128) {
        for (int j = 0; j < 8; ++j) {
            int f = t + 256 * j;             // f < 2048
            int row = f >> 5;                // 32 float4 per row
            int kq = f & 31;
            int gr = base + row;
            float4 v = {0.f, 0.f, 0.f, 0.f};
            if (gr < NN) v = *(const float4*)(hin + (long long)gr * 128 + kq * 4);
            *(float4*)&hl[row][kq * 4] = v;
        }
    } else {  // K == 32
        for (int j = 0; j < 2; ++j) {
            int f = t + 256 * j;             // f < 512
            int row = f >> 3;                // 8 float4 per row
            int kq = f & 7;
            int gr = base + row;
            float4 v = {0.f, 0.f, 0.f, 0.f};
            if (gr < NN) v = *(const float4*)(hin + (long long)gr * 32 + kq * 4);
            *(float4*)&hl[row][kq * 4] = v;
        }
    }
    __syncthreads();

    int cg = t & 31, c0 = cg * 4;
    int rq = t >> 5, r0 = rq * 8;
    float4 acc[8];
    #pragma unroll
    for (int i = 0; i < 8; ++i) acc[i] = make_float4(0.f, 0.f, 0.f, 0.f);

    for (int k4 = 0; k4 < K / 4; ++k4) {
        float4 w0 = *(const float4*)(W + (k4 * 4 + 0) * 128 + c0);
        float4 w1 = *(const float4*)(W + (k4 * 4 + 1) * 128 + c0);
        float4 w2 = *(const float4*)(W + (k4 * 4 + 2) * 128 + c0);
        float4 w3 = *(const float4*)(W + (k4 * 4 + 3) * 128 + c0);
        #pragma unroll
        for (int i = 0; i < 8; ++i) {
            float4 hv = *(const float4*)&hl[r0 + i][k4 * 4];
            acc[i].x += hv.x * w0.x + hv.y * w1.x + hv.z * w2.x + hv.w * w3.x;
            acc[i].y += hv.x * w0.y + hv.y * w1.y + hv.z * w2.y + hv.w * w3.y;
            acc[i].z += hv.x * w0.z + hv.y * w1.z + hv.z * w2.z + hv.w * w3.z;
            acc[i].w += hv.x * w0.w + hv.y * w1.w + hv.z * w2.w + hv.w * w3.w;
        }
    }

    // epilogue: store hp, reduce es/ed over this head's 32 dims (8 lanes x 4)
    int head = cg >> 3;
    int d0 = (cg & 7) * 4;
    float4 as4 = *(const float4*)(asrc + head * 32 + d0);
    float4 ad4 = *(const float4*)(adst + head * 32 + d0);
    #pragma unroll
    for (int i = 0; i < 8; ++i) {
        int gr = base + r0 + i;
        if (gr >= NN) break;
        *(float4*)(hp + (long long)gr * 128 + c0) = acc[i];
        float ps = acc[i].x * as4.x + acc[i].y * as4.y + acc[i].z * as4.z + acc[i].w * as4.w;
        float pd = acc[i].x * ad4.x + acc[i].y * ad4.y + acc[i].z * ad4.z + acc[i].w * ad4.w;
        for (int off = 1; off < 8; off <<= 1) {
            ps += __shfl_xor(ps, off, 8);
            pd += __shfl_xor(pd, off, 8);
        }
        if ((cg & 7) == 0) {
            es[gr * 4 + head] = ps;
            ed[gr * 4 + head] = pd;
        }
    }
}

// ============================ CSR build (once) ============================

__global__ void count_deg(const int* __restrict__ ei, int* __restrict__ deg) {
    int e = blockIdx.x * 256 + threadIdx.x;
    if (e >= ET) return;
    int dst = (e < NE) ? ei[NE + e] : e - NE;
    atomicAdd(deg + dst, 1);
}

#define SCAN_T 1024
#define CHUNK 98            // 1024*98 = 100352 >= NN
__global__ __launch_bounds__(SCAN_T) void scan_deg(const int* __restrict__ deg,
                                                   int* __restrict__ row_ptr) {
    __shared__ int ps[SCAN_T];
    int t = threadIdx.x;
    int base = t * CHUNK;
    int s = 0;
    for (int i = 0; i < CHUNK; ++i) {
        int idx = base + i;
        if (idx < NN) s += deg[idx];
    }
    ps[t] = s;
    __syncthreads();
    for (int off = 1; off < SCAN_T; off <<= 1) {
        int v = (t >= off) ? ps[t - off] : 0;
        __syncthreads();
        ps[t] += v;
        __syncthreads();
    }
    int run = (t == 0) ? 0 : ps[t - 1];
    for (int i = 0; i < CHUNK; ++i) {
        int idx = base + i;
        if (idx < NN) { row_ptr[idx] = run; run += deg[idx]; }
    }
    if (t == SCAN_T - 1) row_ptr[NN] = run;
}

__global__ void fill_csr(const int* __restrict__ ei, int* __restrict__ cursor,
                         int* __restrict__ col) {
    int e = blockIdx.x * 256 + threadIdx.x;
    if (e >= ET) return;
    int src, dst;
    if (e < NE) { src = ei[e]; dst = ei[NE + e]; }
    else        { src = dst = e - NE; }
    int pos = atomicAdd(cursor + dst, 1);
    col[pos] = src;
}

// ==================== fused softmax-aggregate (no atomics) ====================
__global__ void gat_aggregate(const int* __restrict__ row_ptr, const int* __restrict__ col,
                              const float* __restrict__ es, const float* __restrict__ ed,
                              const float* __restrict__ hp, const float* __restrict__ b,
                              float* __restrict__ out) {
    int tid = blockIdx.x * 256 + threadIdx.x;
    int n = tid >> 5;
    int t = tid & 31;
    if (n >= NN) return;
    int head = t >> 3;
    int beg = row_ptr[n], end = row_ptr[n + 1];

    float4 ed4 = *(const float4*)(ed + n * 4);
    float4 m4 = {-1e30f, -1e30f, -1e30f, -1e30f};
    for (int i = beg + t; i < end; i += 32) {
        int s = col[i];
        float4 l = *(const float4*)(es + s * 4);
        l.x += ed4.x; l.y += ed4.y; l.z += ed4.z; l.w += ed4.w;
        l.x = l.x > 0.f ? l.x : 0.2f * l.x;
        l.y = l.y > 0.f ? l.y : 0.2f * l.y;
        l.z = l.z > 0.f ? l.z : 0.2f * l.z;
        l.w = l.w > 0.f ? l.w : 0.2f * l.w;
        m4.x = fmaxf(m4.x, l.x); m4.y = fmaxf(m4.y, l.y);
        m4.z = fmaxf(m4.z, l.z); m4.w = fmaxf(m4.w, l.w);
    }
    for (int off = 1; off < 32; off <<= 1) {
        m4.x = fmaxf(m4.x, __shfl_xor(m4.x, off, 32));
        m4.y = fmaxf(m4.y, __shfl_xor(m4.y, off, 32));
        m4.z = fmaxf(m4.z, __shfl_xor(m4.z, off, 32));
        m4.w = fmaxf(m4.w, __shfl_xor(m4.w, off, 32));
    }
    float m = (head == 0) ? m4.x : (head == 1) ? m4.y : (head == 2) ? m4.z : m4.w;
    float edv = (head == 0) ? ed4.x : (head == 1) ? ed4.y : (head == 2) ? ed4.z : ed4.w;

    float4 acc = {0.f, 0.f, 0.f, 0.f};
    float ws = 0.f;
    for (int i = beg; i < end; ++i) {
        int s = col[i];
        float lv = es[s * 4 + head] + edv;
        lv = lv > 0.f ? lv : 0.2f * lv;
        float w = __expf(lv - m);
        ws += w;
        float4 hv = *(const float4*)(hp + (long long)s * 128 + t * 4);
        acc.x += w * hv.x; acc.y += w * hv.y;
        acc.z += w * hv.z; acc.w += w * hv.w;
    }
    float sv = ws + 1e-16f;
    float4 bv = *(const float4*)(b + t * 4);
    float4 v;
    v.x = acc.x / sv + bv.x;
    v.y = acc.y / sv + bv.y;
    v.z = acc.z / sv + bv.z;
    v.w = acc.w / sv + bv.w;
    v.x = v.x > 0.f ? v.x : expm1f(v.x);
    v.y = v.y > 0.f ? v.y : expm1f(v.y);
    v.z = v.z > 0.f ? v.z : expm1f(v.z);
    v.w = v.w > 0.f ? v.w : expm1f(v.w);
    *(float4*)(out + (long long)n * 128 + t * 4) = v;
}

// ============================ host ============================

extern "C" void kernel_launch(void* const* d_in, const int* in_sizes, int n_in,
                              void* d_out, int out_size, void* d_ws, size_t ws_size,
                              hipStream_t stream) {
    const float* x    = (const float*)d_in[0];
    const int*   ei   = (const int*)d_in[1];
    const float* W_in = (const float*)d_in[2];
    const float* b_in = (const float*)d_in[3];
    const float* W[3]  = {(const float*)d_in[4], (const float*)d_in[8],  (const float*)d_in[12]};
    const float* As[3] = {(const float*)d_in[5], (const float*)d_in[9],  (const float*)d_in[13]};
    const float* Ad[3] = {(const float*)d_in[6], (const float*)d_in[10], (const float*)d_in[14]};
    const float* Bs[3] = {(const float*)d_in[7], (const float*)d_in[11], (const float*)d_in[15]};

    // workspace layout (~75 MB); accb aliases d_out
    float* h0     = (float*)d_ws;                       // NN*32
    float* hp     = h0 + (size_t)NN * 32;               // NN*128
    float* es     = hp + (size_t)NN * 128;              // NN*4
    float* ed     = es + (size_t)NN * 4;                // NN*4
    int*   row_ptr= (int*)(ed + (size_t)NN * 4);        // NN+1
    int*   deg    = row_ptr + (NN + 1);                 // NN
    int*   cursor = deg + NN;                           // NN
    int*   colb   = cursor + NN;                        // ET
    float* accb   = (float*)d_out;                      // NN*128

    // ---- CSR build (graph is static across layers) ----
    hipMemsetAsync(deg, 0, (size_t)NN * sizeof(int), stream);
    count_deg<<<(ET + 255) / 256, 256, 0, stream>>>(ei, deg);
    scan_deg<<<1, SCAN_T, 0, stream>>>(deg, row_ptr);
    hipMemcpyAsync(cursor, row_ptr, (size_t)NN * sizeof(int),
                   hipMemcpyDeviceToDevice, stream);
    fill_csr<<<(ET + 255) / 256, 256, 0, stream>>>(ei, cursor, colb);

    lin_relu2<<<3125, 256, 0, stream>>>(x, W_in, b_in, h0);

    const float* in = h0;
    for (int l = 0; l < 3; ++l) {
        if (l == 0)
            gemm_att2<32><<<1563, 256, 0, stream>>>(in, W[0], As[0], Ad[0], hp, es, ed);
        else
            gemm_att2<128><<<1563, 256, 0, stream>>>(in, W[l], As[l], Ad[l], hp, es, ed);
        gat_aggregate<<<12500, 256, 0, stream>>>(row_ptr, colb, es, ed, hp, Bs[l], accb);
        in = accb;
    }
}

// Round 6
// 855.272 us; speedup vs baseline: 11.3561x; 1.2109x over previous
//
#include <hip/hip_runtime.h>

#define NN 100000
#define NE 1600000
#define ET (NE + NN)   // edges + self-loops = 1,700,000
#define SB 196         // scan blocks: 196*512 = 100352 >= NN

// ============================ dense layers ============================

// ---- h0 = relu(x @ W_in + b_in): x[N,256], W[256,32]. ----
__global__ __launch_bounds__(256) void lin_relu2(const float* __restrict__ x,
                                                 const float* __restrict__ W,
                                                 const float* __restrict__ b,
                                                 float* __restrict__ h) {
    __shared__ float Wl[256 * 32];
    int t = threadIdx.x;
    for (int j = 0; j < 8; ++j) {
        int f = t + 256 * j;                 // f < 2048 float4s
        *(float4*)&Wl[f * 4] = *(const float4*)(W + f * 4);
    }
    __syncthreads();

    int row = (blockIdx.x * 256 + t) >> 3;   // 800000/8 = 100000 exactly
    int c0  = (t & 7) * 4;
    const float* xr = x + (long long)row * 256;
    float4 acc = {0.f, 0.f, 0.f, 0.f};
    for (int k4 = 0; k4 < 64; ++k4) {
        float4 xv = *(const float4*)(xr + k4 * 4);
        float4 w0 = *(const float4*)&Wl[(k4 * 4 + 0) * 32 + c0];
        float4 w1 = *(const float4*)&Wl[(k4 * 4 + 1) * 32 + c0];
        float4 w2 = *(const float4*)&Wl[(k4 * 4 + 2) * 32 + c0];
        float4 w3 = *(const float4*)&Wl[(k4 * 4 + 3) * 32 + c0];
        acc.x += xv.x * w0.x + xv.y * w1.x + xv.z * w2.x + xv.w * w3.x;
        acc.y += xv.x * w0.y + xv.y * w1.y + xv.z * w2.y + xv.w * w3.y;
        acc.z += xv.x * w0.z + xv.y * w1.z + xv.z * w2.z + xv.w * w3.z;
        acc.w += xv.x * w0.w + xv.y * w1.w + xv.z * w2.w + xv.w * w3.w;
    }
    float4 bv = *(const float4*)(b + c0);
    acc.x = fmaxf(acc.x + bv.x, 0.f);
    acc.y = fmaxf(acc.y + bv.y, 0.f);
    acc.z = fmaxf(acc.z + bv.z, 0.f);
    acc.w = fmaxf(acc.w + bv.w, 0.f);
    *(float4*)(h + (long long)row * 32 + c0) = acc;
}

// ---- hp = hin @ W [K x 128] + es/ed logits. 64 rows/block, 8x4 per thread. ----
template<int K>
__global__ __launch_bounds__(256) void gemm_att2(const float* __restrict__ hin,
                                                 const float* __restrict__ W,
                                                 const float* __restrict__ asrc,
                                                 const float* __restrict__ adst,
                                                 float* __restrict__ hp,
                                                 float* __restrict__ es,
                                                 float* __restrict__ ed) {
    __shared__ float hl[64][K + 4];
    int t = threadIdx.x;
    int base = blockIdx.x * 64;

    if (K == 128) {
        for (int j = 0; j < 8; ++j) {
            int f = t + 256 * j;             // f < 2048
            int row = f >> 5;
            int kq = f & 31;
            int gr = base + row;
            float4 v = {0.f, 0.f, 0.f, 0.f};
            if (gr < NN) v = *(const float4*)(hin + (long long)gr * 128 + kq * 4);
            *(float4*)&hl[row][kq * 4] = v;
        }
    } else {  // K == 32
        for (int j = 0; j < 2; ++j) {
            int f = t + 256 * j;             // f < 512
            int row = f >> 3;
            int kq = f & 7;
            int gr = base + row;
            float4 v = {0.f, 0.f, 0.f, 0.f};
            if (gr < NN) v = *(const float4*)(hin + (long long)gr * 32 + kq * 4);
            *(float4*)&hl[row][kq * 4] = v;
        }
    }
    __syncthreads();

    int cg = t & 31, c0 = cg * 4;
    int rq = t >> 5, r0 = rq * 8;
    float4 acc[8];
    #pragma unroll
    for (int i = 0; i < 8; ++i) acc[i] = make_float4(0.f, 0.f, 0.f, 0.f);

    for (int k4 = 0; k4 < K / 4; ++k4) {
        float4 w0 = *(const float4*)(W + (k4 * 4 + 0) * 128 + c0);
        float4 w1 = *(const float4*)(W + (k4 * 4 + 1) * 128 + c0);
        float4 w2 = *(const float4*)(W + (k4 * 4 + 2) * 128 + c0);
        float4 w3 = *(const float4*)(W + (k4 * 4 + 3) * 128 + c0);
        #pragma unroll
        for (int i = 0; i < 8; ++i) {
            float4 hv = *(const float4*)&hl[r0 + i][k4 * 4];
            acc[i].x += hv.x * w0.x + hv.y * w1.x + hv.z * w2.x + hv.w * w3.x;
            acc[i].y += hv.x * w0.y + hv.y * w1.y + hv.z * w2.y + hv.w * w3.y;
            acc[i].z += hv.x * w0.z + hv.y * w1.z + hv.z * w2.z + hv.w * w3.z;
            acc[i].w += hv.x * w0.w + hv.y * w1.w + hv.z * w2.w + hv.w * w3.w;
        }
    }

    int head = cg >> 3;
    int d0 = (cg & 7) * 4;
    float4 as4 = *(const float4*)(asrc + head * 32 + d0);
    float4 ad4 = *(const float4*)(adst + head * 32 + d0);
    #pragma unroll
    for (int i = 0; i < 8; ++i) {
        int gr = base + r0 + i;
        if (gr >= NN) break;
        *(float4*)(hp + (long long)gr * 128 + c0) = acc[i];
        float ps = acc[i].x * as4.x + acc[i].y * as4.y + acc[i].z * as4.z + acc[i].w * as4.w;
        float pd = acc[i].x * ad4.x + acc[i].y * ad4.y + acc[i].z * ad4.z + acc[i].w * ad4.w;
        for (int off = 1; off < 8; off <<= 1) {
            ps += __shfl_xor(ps, off, 8);
            pd += __shfl_xor(pd, off, 8);
        }
        if ((cg & 7) == 0) {
            es[gr * 4 + head] = ps;
            ed[gr * 4 + head] = pd;
        }
    }
}

// ============================ CSR build (once) ============================

__global__ void count_deg(const int* __restrict__ ei, int* __restrict__ deg) {
    int e = blockIdx.x * 256 + threadIdx.x;
    if (e >= ET) return;
    int dst = (e < NE) ? ei[NE + e] : e - NE;
    atomicAdd(deg + dst, 1);
}

// ---- 3-phase parallel exclusive scan of deg[NN] -> row_ptr[NN+1] ----
__global__ __launch_bounds__(256) void scan1(const int* __restrict__ deg,
                                             int* __restrict__ tpre,
                                             int* __restrict__ bsum) {
    __shared__ int ls[256];
    int t = threadIdx.x, b = blockIdx.x;
    int i0 = b * 512 + t * 2;
    int d0 = (i0 < NN) ? deg[i0] : 0;
    int d1 = (i0 + 1 < NN) ? deg[i0 + 1] : 0;
    int local = d0 + d1;
    ls[t] = local;
    __syncthreads();
    for (int off = 1; off < 256; off <<= 1) {
        int v = (t >= off) ? ls[t - off] : 0;
        __syncthreads();
        ls[t] += v;
        __syncthreads();
    }
    tpre[b * 256 + t] = ls[t] - local;      // exclusive prefix within block
    if (t == 255) bsum[b] = ls[255];
}

__global__ __launch_bounds__(256) void scan2(const int* __restrict__ bsum,
                                             int* __restrict__ boff) {
    __shared__ int ls[256];
    int t = threadIdx.x;
    int v = (t < SB) ? bsum[t] : 0;
    ls[t] = v;
    __syncthreads();
    for (int off = 1; off < 256; off <<= 1) {
        int u = (t >= off) ? ls[t - off] : 0;
        __syncthreads();
        ls[t] += u;
        __syncthreads();
    }
    if (t < SB) boff[t] = ls[t] - v;        // exclusive block offset
}

__global__ __launch_bounds__(256) void scan3(const int* __restrict__ deg,
                                             const int* __restrict__ tpre,
                                             const int* __restrict__ boff,
                                             int* __restrict__ row_ptr) {
    int t = threadIdx.x, b = blockIdx.x;
    int i0 = b * 512 + t * 2;
    int p = boff[b] + tpre[b * 256 + t];
    if (i0 < NN)     row_ptr[i0] = p;
    if (i0 + 1 < NN) row_ptr[i0 + 1] = p + deg[i0];
    if (b == 0 && t == 0) row_ptr[NN] = ET;
}

__global__ void fill_csr(const int* __restrict__ ei, int* __restrict__ cursor,
                         int* __restrict__ col) {
    int e = blockIdx.x * 256 + threadIdx.x;
    if (e >= ET) return;
    int src, dst;
    if (e < NE) { src = ei[e]; dst = ei[NE + e]; }
    else        { src = dst = e - NE; }
    int pos = atomicAdd(cursor + dst, 1);
    col[pos] = src;
}

// ==================== fused softmax-aggregate (no atomics) ====================
__global__ void gat_aggregate(const int* __restrict__ row_ptr, const int* __restrict__ col,
                              const float* __restrict__ es, const float* __restrict__ ed,
                              const float* __restrict__ hp, const float* __restrict__ b,
                              float* __restrict__ out) {
    int tid = blockIdx.x * 256 + threadIdx.x;
    int n = tid >> 5;
    int t = tid & 31;
    if (n >= NN) return;
    int head = t >> 3;
    int beg = row_ptr[n], end = row_ptr[n + 1];

    float4 ed4 = *(const float4*)(ed + n * 4);
    float4 m4 = {-1e30f, -1e30f, -1e30f, -1e30f};
    for (int i = beg + t; i < end; i += 32) {
        int s = col[i];
        float4 l = *(const float4*)(es + s * 4);
        l.x += ed4.x; l.y += ed4.y; l.z += ed4.z; l.w += ed4.w;
        l.x = l.x > 0.f ? l.x : 0.2f * l.x;
        l.y = l.y > 0.f ? l.y : 0.2f * l.y;
        l.z = l.z > 0.f ? l.z : 0.2f * l.z;
        l.w = l.w > 0.f ? l.w : 0.2f * l.w;
        m4.x = fmaxf(m4.x, l.x); m4.y = fmaxf(m4.y, l.y);
        m4.z = fmaxf(m4.z, l.z); m4.w = fmaxf(m4.w, l.w);
    }
    for (int off = 1; off < 32; off <<= 1) {
        m4.x = fmaxf(m4.x, __shfl_xor(m4.x, off, 32));
        m4.y = fmaxf(m4.y, __shfl_xor(m4.y, off, 32));
        m4.z = fmaxf(m4.z, __shfl_xor(m4.z, off, 32));
        m4.w = fmaxf(m4.w, __shfl_xor(m4.w, off, 32));
    }
    float m = (head == 0) ? m4.x : (head == 1) ? m4.y : (head == 2) ? m4.z : m4.w;
    float edv = (head == 0) ? ed4.x : (head == 1) ? ed4.y : (head == 2) ? ed4.z : ed4.w;

    float4 acc = {0.f, 0.f, 0.f, 0.f};
    float ws = 0.f;
    for (int i = beg; i < end; ++i) {
        int s = col[i];
        float lv = es[s * 4 + head] + edv;
        lv = lv > 0.f ? lv : 0.2f * lv;
        float w = __expf(lv - m);
        ws += w;
        float4 hv = *(const float4*)(hp + (long long)s * 128 + t * 4);
        acc.x += w * hv.x; acc.y += w * hv.y;
        acc.z += w * hv.z; acc.w += w * hv.w;
    }
    float sv = ws + 1e-16f;
    float4 bv = *(const float4*)(b + t * 4);
    float4 v;
    v.x = acc.x / sv + bv.x;
    v.y = acc.y / sv + bv.y;
    v.z = acc.z / sv + bv.z;
    v.w = acc.w / sv + bv.w;
    v.x = v.x > 0.f ? v.x : expm1f(v.x);
    v.y = v.y > 0.f ? v.y : expm1f(v.y);
    v.z = v.z > 0.f ? v.z : expm1f(v.z);
    v.w = v.w > 0.f ? v.w : expm1f(v.w);
    *(float4*)(out + (long long)n * 128 + t * 4) = v;
}

// ============================ host ============================

extern "C" void kernel_launch(void* const* d_in, const int* in_sizes, int n_in,
                              void* d_out, int out_size, void* d_ws, size_t ws_size,
                              hipStream_t stream) {
    const float* x    = (const float*)d_in[0];
    const int*   ei   = (const int*)d_in[1];
    const float* W_in = (const float*)d_in[2];
    const float* b_in = (const float*)d_in[3];
    const float* W[3]  = {(const float*)d_in[4], (const float*)d_in[8],  (const float*)d_in[12]};
    const float* As[3] = {(const float*)d_in[5], (const float*)d_in[9],  (const float*)d_in[13]};
    const float* Ad[3] = {(const float*)d_in[6], (const float*)d_in[10], (const float*)d_in[14]};
    const float* Bs[3] = {(const float*)d_in[7], (const float*)d_in[11], (const float*)d_in[15]};

    // workspace layout (~76 MB); accb aliases d_out
    float* h0     = (float*)d_ws;                       // NN*32
    float* hp     = h0 + (size_t)NN * 32;               // NN*128
    float* es     = hp + (size_t)NN * 128;              // NN*4
    float* ed     = es + (size_t)NN * 4;                // NN*4
    int*   row_ptr= (int*)(ed + (size_t)NN * 4);        // NN+1
    int*   deg    = row_ptr + (NN + 1);                 // NN
    int*   cursor = deg + NN;                           // NN
    int*   tpre   = cursor + NN;                        // SB*256
    int*   bsum   = tpre + SB * 256;                    // SB
    int*   boff   = bsum + SB;                          // SB
    int*   colb   = boff + SB;                          // ET
    float* accb   = (float*)d_out;                      // NN*128

    // ---- CSR build (graph is static across layers) ----
    hipMemsetAsync(deg, 0, (size_t)NN * sizeof(int), stream);
    count_deg<<<(ET + 255) / 256, 256, 0, stream>>>(ei, deg);
    scan1<<<SB, 256, 0, stream>>>(deg, tpre, bsum);
    scan2<<<1, 256, 0, stream>>>(bsum, boff);
    scan3<<<SB, 256, 0, stream>>>(deg, tpre, boff, row_ptr);
    hipMemcpyAsync(cursor, row_ptr, (size_t)NN * sizeof(int),
                   hipMemcpyDeviceToDevice, stream);
    fill_csr<<<(ET + 255) / 256, 256, 0, stream>>>(ei, cursor, colb);

    lin_relu2<<<3125, 256, 0, stream>>>(x, W_in, b_in, h0);

    const float* in = h0;
    for (int l = 0; l < 3; ++l) {
        if (l == 0)
            gemm_att2<32><<<1563, 256, 0, stream>>>(in, W[0], As[0], Ad[0], hp, es, ed);
        else
            gemm_att2<128><<<1563, 256, 0, stream>>>(in, W[l], As[l], Ad[l], hp, es, ed);
        gat_aggregate<<<12500, 256, 0, stream>>>(row_ptr, colb, es, ed, hp, Bs[l], accb);
        in = accb;
    }
}

// Round 7
// 835.927 us; speedup vs baseline: 11.6189x; 1.0231x over previous
//
#include <hip/hip_runtime.h>

#define NN 100000
#define NE 1600000
#define ET (NE + NN)   // edges + self-loops = 1,700,000
#define SB 196         // scan blocks: 196*512 = 100352 >= NN

// ============================ dense layers ============================

// ---- h0 = relu(x @ W_in + b_in): x[N,256], W[256,32]. ----
__global__ __launch_bounds__(256) void lin_relu2(const float* __restrict__ x,
                                                 const float* __restrict__ W,
                                                 const float* __restrict__ b,
                                                 float* __restrict__ h) {
    __shared__ float Wl[256 * 32];
    int t = threadIdx.x;
    for (int j = 0; j < 8; ++j) {
        int f = t + 256 * j;                 // f < 2048 float4s
        *(float4*)&Wl[f * 4] = *(const float4*)(W + f * 4);
    }
    __syncthreads();

    int row = (blockIdx.x * 256 + t) >> 3;   // 800000/8 = 100000 exactly
    int c0  = (t & 7) * 4;
    const float* xr = x + (long long)row * 256;
    float4 acc = {0.f, 0.f, 0.f, 0.f};
    for (int k4 = 0; k4 < 64; ++k4) {
        float4 xv = *(const float4*)(xr + k4 * 4);
        float4 w0 = *(const float4*)&Wl[(k4 * 4 + 0) * 32 + c0];
        float4 w1 = *(const float4*)&Wl[(k4 * 4 + 1) * 32 + c0];
        float4 w2 = *(const float4*)&Wl[(k4 * 4 + 2) * 32 + c0];
        float4 w3 = *(const float4*)&Wl[(k4 * 4 + 3) * 32 + c0];
        acc.x += xv.x * w0.x + xv.y * w1.x + xv.z * w2.x + xv.w * w3.x;
        acc.y += xv.x * w0.y + xv.y * w1.y + xv.z * w2.y + xv.w * w3.y;
        acc.z += xv.x * w0.z + xv.y * w1.z + xv.z * w2.z + xv.w * w3.z;
        acc.w += xv.x * w0.w + xv.y * w1.w + xv.z * w2.w + xv.w * w3.w;
    }
    float4 bv = *(const float4*)(b + c0);
    acc.x = fmaxf(acc.x + bv.x, 0.f);
    acc.y = fmaxf(acc.y + bv.y, 0.f);
    acc.z = fmaxf(acc.z + bv.z, 0.f);
    acc.w = fmaxf(acc.w + bv.w, 0.f);
    *(float4*)(h + (long long)row * 32 + c0) = acc;
}

// ---- hp = hin @ W [K x 128] + es/ed logits. ----
// 128 rows/block; thread = 16 rows x 4 cols (64 f32 acc). hin tile in LDS (64KB for K=128).
// hl reads are wave-broadcast (all 32 lanes same addr) -> no bank conflicts, no pad.
template<int K>
__global__ __launch_bounds__(256) void gemm_att3(const float* __restrict__ hin,
                                                 const float* __restrict__ W,
                                                 const float* __restrict__ asrc,
                                                 const float* __restrict__ adst,
                                                 float* __restrict__ hp,
                                                 float* __restrict__ es,
                                                 float* __restrict__ ed) {
    __shared__ float hl[128 * K];
    int t = threadIdx.x;
    int base = blockIdx.x * 128;

    const int F4R = K / 4;                   // float4 per row: 32 or 8
    for (int f = t; f < 128 * F4R; f += 256) {
        int row = f / F4R;
        int kq  = f % F4R;
        int gr  = base + row;
        float4 v = {0.f, 0.f, 0.f, 0.f};
        if (gr < NN) v = *(const float4*)(hin + (long long)gr * K + kq * 4);
        *(float4*)&hl[row * K + kq * 4] = v;
    }
    __syncthreads();

    int cg = t & 31, c0 = cg * 4;
    int rq = t >> 5, r0 = rq * 16;
    float4 acc[16];
    #pragma unroll
    for (int i = 0; i < 16; ++i) acc[i] = make_float4(0.f, 0.f, 0.f, 0.f);

    for (int k4 = 0; k4 < K / 4; ++k4) {
        float4 w0 = *(const float4*)(W + (k4 * 4 + 0) * 128 + c0);
        float4 w1 = *(const float4*)(W + (k4 * 4 + 1) * 128 + c0);
        float4 w2 = *(const float4*)(W + (k4 * 4 + 2) * 128 + c0);
        float4 w3 = *(const float4*)(W + (k4 * 4 + 3) * 128 + c0);
        #pragma unroll
        for (int i = 0; i < 16; ++i) {
            float4 hv = *(const float4*)&hl[(r0 + i) * K + k4 * 4];
            acc[i].x += hv.x * w0.x + hv.y * w1.x + hv.z * w2.x + hv.w * w3.x;
            acc[i].y += hv.x * w0.y + hv.y * w1.y + hv.z * w2.y + hv.w * w3.y;
            acc[i].z += hv.x * w0.z + hv.y * w1.z + hv.z * w2.z + hv.w * w3.z;
            acc[i].w += hv.x * w0.w + hv.y * w1.w + hv.z * w2.w + hv.w * w3.w;
        }
    }

    int head = cg >> 3;
    int d0 = (cg & 7) * 4;
    float4 as4 = *(const float4*)(asrc + head * 32 + d0);
    float4 ad4 = *(const float4*)(adst + head * 32 + d0);
    #pragma unroll
    for (int i = 0; i < 16; ++i) {
        int gr = base + r0 + i;
        if (gr >= NN) break;
        *(float4*)(hp + (long long)gr * 128 + c0) = acc[i];
        float ps = acc[i].x * as4.x + acc[i].y * as4.y + acc[i].z * as4.z + acc[i].w * as4.w;
        float pd = acc[i].x * ad4.x + acc[i].y * ad4.y + acc[i].z * ad4.z + acc[i].w * ad4.w;
        for (int off = 1; off < 8; off <<= 1) {
            ps += __shfl_xor(ps, off, 8);
            pd += __shfl_xor(pd, off, 8);
        }
        if ((cg & 7) == 0) {
            es[gr * 4 + head] = ps;
            ed[gr * 4 + head] = pd;
        }
    }
}

// ============================ CSR build (once) ============================

__global__ void count_deg(const int* __restrict__ ei, int* __restrict__ deg) {
    int e = blockIdx.x * 256 + threadIdx.x;
    if (e >= ET) return;
    int dst = (e < NE) ? ei[NE + e] : e - NE;
    atomicAdd(deg + dst, 1);
}

__global__ __launch_bounds__(256) void scan1(const int* __restrict__ deg,
                                             int* __restrict__ tpre,
                                             int* __restrict__ bsum) {
    __shared__ int ls[256];
    int t = threadIdx.x, b = blockIdx.x;
    int i0 = b * 512 + t * 2;
    int d0 = (i0 < NN) ? deg[i0] : 0;
    int d1 = (i0 + 1 < NN) ? deg[i0 + 1] : 0;
    int local = d0 + d1;
    ls[t] = local;
    __syncthreads();
    for (int off = 1; off < 256; off <<= 1) {
        int v = (t >= off) ? ls[t - off] : 0;
        __syncthreads();
        ls[t] += v;
        __syncthreads();
    }
    tpre[b * 256 + t] = ls[t] - local;
    if (t == 255) bsum[b] = ls[255];
}

__global__ __launch_bounds__(256) void scan2(const int* __restrict__ bsum,
                                             int* __restrict__ boff) {
    __shared__ int ls[256];
    int t = threadIdx.x;
    int v = (t < SB) ? bsum[t] : 0;
    ls[t] = v;
    __syncthreads();
    for (int off = 1; off < 256; off <<= 1) {
        int u = (t >= off) ? ls[t - off] : 0;
        __syncthreads();
        ls[t] += u;
        __syncthreads();
    }
    if (t < SB) boff[t] = ls[t] - v;
}

__global__ __launch_bounds__(256) void scan3(const int* __restrict__ deg,
                                             const int* __restrict__ tpre,
                                             const int* __restrict__ boff,
                                             int* __restrict__ row_ptr) {
    int t = threadIdx.x, b = blockIdx.x;
    int i0 = b * 512 + t * 2;
    int p = boff[b] + tpre[b * 256 + t];
    if (i0 < NN)     row_ptr[i0] = p;
    if (i0 + 1 < NN) row_ptr[i0 + 1] = p + deg[i0];
    if (b == 0 && t == 0) row_ptr[NN] = ET;
}

__global__ void fill_csr(const int* __restrict__ ei, int* __restrict__ cursor,
                         int* __restrict__ col) {
    int e = blockIdx.x * 256 + threadIdx.x;
    if (e >= ET) return;
    int src, dst;
    if (e < NE) { src = ei[e]; dst = ei[NE + e]; }
    else        { src = dst = e - NE; }
    int pos = atomicAdd(cursor + dst, 1);
    col[pos] = src;
}

// ==================== fused softmax-aggregate (no atomics) ====================
__global__ void gat_aggregate(const int* __restrict__ row_ptr, const int* __restrict__ col,
                              const float* __restrict__ es, const float* __restrict__ ed,
                              const float* __restrict__ hp, const float* __restrict__ b,
                              float* __restrict__ out) {
    int tid = blockIdx.x * 256 + threadIdx.x;
    int n = tid >> 5;
    int t = tid & 31;
    if (n >= NN) return;
    int head = t >> 3;
    int beg = row_ptr[n], end = row_ptr[n + 1];

    float4 ed4 = *(const float4*)(ed + n * 4);
    // phase 1: per-head max (lane-strided)
    float4 m4 = {-1e30f, -1e30f, -1e30f, -1e30f};
    for (int i = beg + t; i < end; i += 32) {
        int s = col[i];
        float4 l = *(const float4*)(es + s * 4);
        l.x += ed4.x; l.y += ed4.y; l.z += ed4.z; l.w += ed4.w;
        l.x = l.x > 0.f ? l.x : 0.2f * l.x;
        l.y = l.y > 0.f ? l.y : 0.2f * l.y;
        l.z = l.z > 0.f ? l.z : 0.2f * l.z;
        l.w = l.w > 0.f ? l.w : 0.2f * l.w;
        m4.x = fmaxf(m4.x, l.x); m4.y = fmaxf(m4.y, l.y);
        m4.z = fmaxf(m4.z, l.z); m4.w = fmaxf(m4.w, l.w);
    }
    for (int off = 1; off < 32; off <<= 1) {
        m4.x = fmaxf(m4.x, __shfl_xor(m4.x, off, 32));
        m4.y = fmaxf(m4.y, __shfl_xor(m4.y, off, 32));
        m4.z = fmaxf(m4.z, __shfl_xor(m4.z, off, 32));
        m4.w = fmaxf(m4.w, __shfl_xor(m4.w, off, 32));
    }
    float m = (head == 0) ? m4.x : (head == 1) ? m4.y : (head == 2) ? m4.z : m4.w;
    float edv = (head == 0) ? ed4.x : (head == 1) ? ed4.y : (head == 2) ? ed4.z : ed4.w;

    // phase 2: serial walk, 2-way unrolled for memory-level parallelism
    float4 acc = {0.f, 0.f, 0.f, 0.f};
    float ws = 0.f;
    int i = beg;
    for (; i + 1 < end; i += 2) {
        int s0 = col[i];
        int s1 = col[i + 1];
        float lv0 = es[s0 * 4 + head] + edv;
        float lv1 = es[s1 * 4 + head] + edv;
        float4 hv0 = *(const float4*)(hp + (long long)s0 * 128 + t * 4);
        float4 hv1 = *(const float4*)(hp + (long long)s1 * 128 + t * 4);
        lv0 = lv0 > 0.f ? lv0 : 0.2f * lv0;
        lv1 = lv1 > 0.f ? lv1 : 0.2f * lv1;
        float w0 = __expf(lv0 - m);
        float w1 = __expf(lv1 - m);
        ws += w0 + w1;
        acc.x += w0 * hv0.x + w1 * hv1.x;
        acc.y += w0 * hv0.y + w1 * hv1.y;
        acc.z += w0 * hv0.z + w1 * hv1.z;
        acc.w += w0 * hv0.w + w1 * hv1.w;
    }
    if (i < end) {
        int s = col[i];
        float lv = es[s * 4 + head] + edv;
        lv = lv > 0.f ? lv : 0.2f * lv;
        float w = __expf(lv - m);
        ws += w;
        float4 hv = *(const float4*)(hp + (long long)s * 128 + t * 4);
        acc.x += w * hv.x; acc.y += w * hv.y;
        acc.z += w * hv.z; acc.w += w * hv.w;
    }
    float sv = ws + 1e-16f;
    float4 bv = *(const float4*)(b + t * 4);
    float4 v;
    v.x = acc.x / sv + bv.x;
    v.y = acc.y / sv + bv.y;
    v.z = acc.z / sv + bv.z;
    v.w = acc.w / sv + bv.w;
    v.x = v.x > 0.f ? v.x : expm1f(v.x);
    v.y = v.y > 0.f ? v.y : expm1f(v.y);
    v.z = v.z > 0.f ? v.z : expm1f(v.z);
    v.w = v.w > 0.f ? v.w : expm1f(v.w);
    *(float4*)(out + (long long)n * 128 + t * 4) = v;
}

// ============================ host ============================

extern "C" void kernel_launch(void* const* d_in, const int* in_sizes, int n_in,
                              void* d_out, int out_size, void* d_ws, size_t ws_size,
                              hipStream_t stream) {
    const float* x    = (const float*)d_in[0];
    const int*   ei   = (const int*)d_in[1];
    const float* W_in = (const float*)d_in[2];
    const float* b_in = (const float*)d_in[3];
    const float* W[3]  = {(const float*)d_in[4], (const float*)d_in[8],  (const float*)d_in[12]};
    const float* As[3] = {(const float*)d_in[5], (const float*)d_in[9],  (const float*)d_in[13]};
    const float* Ad[3] = {(const float*)d_in[6], (const float*)d_in[10], (const float*)d_in[14]};
    const float* Bs[3] = {(const float*)d_in[7], (const float*)d_in[11], (const float*)d_in[15]};

    // workspace layout (~76 MB); accb aliases d_out
    float* h0     = (float*)d_ws;                       // NN*32
    float* hp     = h0 + (size_t)NN * 32;               // NN*128
    float* es     = hp + (size_t)NN * 128;              // NN*4
    float* ed     = es + (size_t)NN * 4;                // NN*4
    int*   row_ptr= (int*)(ed + (size_t)NN * 4);        // NN+1
    int*   deg    = row_ptr + (NN + 1);                 // NN
    int*   cursor = deg + NN;                           // NN
    int*   tpre   = cursor + NN;                        // SB*256
    int*   bsum   = tpre + SB * 256;                    // SB
    int*   boff   = bsum + SB;                          // SB
    int*   colb   = boff + SB;                          // ET
    float* accb   = (float*)d_out;                      // NN*128

    // ---- CSR build (graph is static across layers) ----
    hipMemsetAsync(deg, 0, (size_t)NN * sizeof(int), stream);
    count_deg<<<(ET + 255) / 256, 256, 0, stream>>>(ei, deg);
    scan1<<<SB, 256, 0, stream>>>(deg, tpre, bsum);
    scan2<<<1, 256, 0, stream>>>(bsum, boff);
    scan3<<<SB, 256, 0, stream>>>(deg, tpre, boff, row_ptr);
    hipMemcpyAsync(cursor, row_ptr, (size_t)NN * sizeof(int),
                   hipMemcpyDeviceToDevice, stream);
    fill_csr<<<(ET + 255) / 256, 256, 0, stream>>>(ei, cursor, colb);

    lin_relu2<<<3125, 256, 0, stream>>>(x, W_in, b_in, h0);

    const float* in = h0;
    for (int l = 0; l < 3; ++l) {
        if (l == 0)
            gemm_att3<32><<<782, 256, 0, stream>>>(in, W[0], As[0], Ad[0], hp, es, ed);
        else
            gemm_att3<128><<<782, 256, 0, stream>>>(in, W[l], As[l], Ad[l], hp, es, ed);
        gat_aggregate<<<12500, 256, 0, stream>>>(row_ptr, colb, es, ed, hp, Bs[l], accb);
        in = accb;
    }
}